// Round 9
// baseline (233.207 us; speedup 1.0000x reference)
//
#include <hip/hip_runtime.h>
#include <cmath>
#include <cstdint>

#define NB 8
#define NPROP 1000
#define NCLS 80
#define NLOG 81
#define KCAND 1024
#define NTH 10
#define DFEAT 2048
#define NOBJ 6
#define NSCORE (NPROP*NCLS)   // 80000
#define HBLK 8                // softhist blocks per image
#define PCHUNK (NPROP/HBLK)   // 125
#define CCAP 64               // per-class candidate capacity (mean ~13)

// ---------------- workspace layout (bytes) ----------------
constexpr size_t OFF_SCORES = 0;
constexpr size_t SZ_SCORES  = (size_t)NB * NSCORE * 4;                 // 2,560,000
constexpr size_t OFF_H1     = OFF_SCORES + SZ_SCORES;                  // 64*2048*4 = 524,288

__device__ __forceinline__ float nms_th(int t) {
    // replicates float32(np.arange(0.001, 1.0, 0.1)[t])
    return (float)(0.001 + 0.1 * (double)t);
}

// monotone key: ascending u64 order == (score desc, flat idx asc) == lax.top_k order
__device__ __forceinline__ unsigned score_vkey(float v) {
    float vv = (v > 1e-4f) ? v : -1.0f;
    unsigned bits = __float_as_uint(vv);
    unsigned u = (bits & 0x80000000u) ? ~bits : (bits | 0x80000000u);
    return ~u;
}

// K_A: fused softmax + scores write + level-1 histogram (vkey bits [31:21])
__global__ __launch_bounds__(1024) void k_softhist(const float* __restrict__ logits,
                                                   float* __restrict__ scores,
                                                   unsigned* __restrict__ hist1) {
    __shared__ unsigned hh[2048];
    int img = blockIdx.x >> 3, blk = blockIdx.x & 7;
    int tid = threadIdx.x, wid = tid >> 6, lane = tid & 63;
    hh[tid] = 0; hh[tid + 1024] = 0;
    __syncthreads();
    for (int p = wid; p < PCHUNK; p += 16) {
        int prop = blk * PCHUNK + p;
        const float* L = logits + ((size_t)img * NPROP + prop) * NLOG;
        float l0 = L[lane];
        float l1 = (lane < 17) ? L[64 + lane] : -INFINITY;
        float m = fmaxf(l0, l1);
        #pragma unroll
        for (int o = 32; o > 0; o >>= 1) m = fmaxf(m, __shfl_xor(m, o, 64));
        float e0 = expf(l0 - m);
        float e1 = (lane < 17) ? expf(l1 - m) : 0.f;
        float s = e0 + e1;
        #pragma unroll
        for (int o = 32; o > 0; o >>= 1) s += __shfl_xor(s, o, 64);
        float* op = scores + ((size_t)img * NPROP + prop) * NCLS;
        float p0 = e0 / s;
        op[lane] = p0;
        atomicAdd(&hh[score_vkey(p0) >> 21], 1u);
        if (lane < 16) {
            float p1 = e1 / s;
            op[64 + lane] = p1;
            atomicAdd(&hh[score_vkey(p1) >> 21], 1u);
        }
    }
    __syncthreads();
    unsigned* outp = hist1 + ((size_t)img * HBLK + blk) * 2048;
    outp[tid] = hh[tid];
    outp[tid + 1024] = hh[tid + 1024];
}

// 1024-thread block scan over 2048 LDS bins: crossing bin for rank K.
// Writes shared *out_b/*out_rem from the crossing thread; caller barriers after.
__device__ __forceinline__ void pivot_lds(const unsigned* __restrict__ h, unsigned K,
                                          int* __restrict__ out_b, int* __restrict__ out_rem,
                                          unsigned* __restrict__ wsum) {
    int tid = threadIdx.x;
    unsigned a = h[2 * tid], b = h[2 * tid + 1];
    unsigned p = a + b;
    unsigned x = p;
    #pragma unroll
    for (int d = 1; d < 64; d <<= 1) {
        unsigned y = __shfl_up(x, (unsigned)d, 64);
        if ((tid & 63) >= d) x += y;
    }
    if ((tid & 63) == 63) wsum[tid >> 6] = x;
    __syncthreads();
    if (tid < 16) {
        unsigned w = wsum[tid];
        #pragma unroll
        for (int d = 1; d < 16; d <<= 1) {
            unsigned y = __shfl_up(w, (unsigned)d, 64);
            if (tid >= d) w += y;
        }
        wsum[tid] = w;
    }
    __syncthreads();
    unsigned wex = (tid >= 64) ? wsum[(tid >> 6) - 1] : 0u;
    unsigned E = x + wex - p;   // exclusive prefix before bin 2*tid
    if (E < K && E + a >= K)              { *out_b = 2 * tid;     *out_rem = (int)(K - E); }
    else if (E + a < K && E + a + b >= K) { *out_b = 2 * tid + 1; *out_rem = (int)(K - (E + a)); }
}

// K_B: one block per image — pivot1, hist2, pivot2, gather, sort, candidates,
// per-class NMS, threshold select, feature gather. LDS phase overlays:
//   [0,20480):  hist(ph1, 8KB) -> keys(ph2-4, 16KB) -> clist(ph5, 20KB)
//   [24576,49152): cand arrays   [49152,...): valid/ccnt/keeps/scnt
__global__ __launch_bounds__(1024) void k_mega2(const float* __restrict__ scores,
                                                const unsigned* __restrict__ hist1,
                                                const float* __restrict__ boxes,
                                                const int* __restrict__ hw,
                                                const float* __restrict__ feats,
                                                float* __restrict__ outp) {
    __shared__ __align__(16) unsigned char smem[51200];
    unsigned*           hist  = (unsigned*)(smem);                 // [2048]
    unsigned long long* keys  = (unsigned long long*)(smem);       // [2048]
    int*                clist = (int*)(smem);                      // [80*64]
    float* bx1 = (float*)(smem + 24576);
    float* by1 = (float*)(smem + 28672);
    float* bx2 = (float*)(smem + 32768);
    float* by2 = (float*)(smem + 36864);
    float* bar = (float*)(smem + 40960);
    int*   bprop = (int*)(smem + 45056);
    unsigned long long* bvalid = (unsigned long long*)(smem + 49152);  // [16]
    int*   ccnt  = (int*)(smem + 49280);                               // [80]
    unsigned long long* keep10 = (unsigned long long*)(smem + 49600);  // [10*16]
    int*   scnt  = (int*)(smem + 50880);                               // [10]
    __shared__ unsigned wsum[16];
    __shared__ int sb1, sr1, sb2, sr2, stsel;
    __shared__ int sids[NOBJ];
    __shared__ unsigned scounter;

    const int img = blockIdx.x;
    const int tid = threadIdx.x;
    const int wv  = tid >> 6, lane = tid & 63;
    const float* sc = scores + (size_t)img * NSCORE;

    // ---- P1: pivot1 from global hist1 (sum 8 slices into LDS) ----
    {
        const unsigned* h8 = hist1 + (size_t)img * HBLK * 2048;
        unsigned s0 = 0, s1 = 0;
        #pragma unroll
        for (int s = 0; s < HBLK; ++s) {
            s0 += h8[s * 2048 + tid];
            s1 += h8[s * 2048 + tid + 1024];
        }
        hist[tid] = s0; hist[tid + 1024] = s1;
    }
    __syncthreads();
    pivot_lds(hist, KCAND, &sb1, &sr1, wsum);
    __syncthreads();
    int b1 = sb1, rem1 = sr1;

    // ---- P2: level-2 histogram (bits [20:10]) restricted to bin b1 ----
    hist[tid] = 0; hist[tid + 1024] = 0;
    __syncthreads();
    for (int e = tid; e < NSCORE; e += 1024) {
        unsigned vk = score_vkey(sc[e]);
        if ((int)(vk >> 21) == b1) atomicAdd(&hist[(vk >> 10) & 2047u], 1u);
    }
    __syncthreads();
    pivot_lds(hist, (unsigned)rem1, &sb2, &sr2, wsum);
    __syncthreads();
    unsigned T22 = ((unsigned)b1 << 11) | (unsigned)sb2;

    // ---- P3: gather keys with top22 <= T22 into LDS (overwrites hist) ----
    __syncthreads();
    keys[tid] = ~0ULL; keys[tid + 1024] = ~0ULL;
    if (tid == 0) scounter = 0;
    __syncthreads();
    for (int e = tid; e < NSCORE; e += 1024) {
        unsigned vk = score_vkey(sc[e]);
        if ((vk >> 10) <= T22) {
            unsigned pos = atomicAdd(&scounter, 1u);
            if (pos < 2048) keys[pos] = ((unsigned long long)vk << 32) | (unsigned)e;
        }
    }
    __syncthreads();
    int cnt = (int)scounter; if (cnt > 2048) cnt = 2048;

    // ---- P4: bitonic sort 2048 keys ascending (index == rank after) ----
    for (int k = 2; k <= 2048; k <<= 1) {
        for (int j = k >> 1; j > 0; j >>= 1) {
            #pragma unroll
            for (int s = 0; s < 2; ++s) {
                int i = s * 1024 + tid;
                int ixj = i ^ j;
                if (ixj > i) {
                    bool up = ((i & k) == 0);
                    unsigned long long a = keys[i], b = keys[ixj];
                    if ((a > b) == up) { keys[i] = b; keys[ixj] = a; }
                }
            }
            __syncthreads();
        }
    }

    // ---- P5: candidate decode at rank=tid (exact _rn sequence) ----
    int mycls = -1;
    {
        bool have = (tid < KCAND) && (tid < cnt);
        unsigned long long a = have ? keys[tid] : ~0ULL;
        bool valid = false;
        if (have) {
            unsigned u   = ~(unsigned)(a >> 32);
            unsigned idx = (unsigned)a;
            const unsigned uth = __float_as_uint(1e-4f) | 0x80000000u;
            valid = u > uth;
            int prop = (int)(idx / NCLS);
            int cls  = (int)(idx - (unsigned)prop * NCLS);
            mycls = cls;
            const float4 bx = *(const float4*)(boxes + ((((size_t)img * NPROP + prop) * NCLS + cls) << 2));
            float h = (float)hw[img * 2 + 0];
            float w = (float)hw[img * 2 + 1];
            float x1 = fminf(fmaxf(bx.x, 0.f), w);
            float y1 = fminf(fmaxf(bx.y, 0.f), h);
            float x2 = fminf(fmaxf(bx.z, 0.f), w);
            float y2 = fminf(fmaxf(bx.w, 0.f), h);
            float offc = __fmul_rn((float)cls, 4096.0f);
            x1 = __fadd_rn(x1, offc); y1 = __fadd_rn(y1, offc);
            x2 = __fadd_rn(x2, offc); y2 = __fadd_rn(y2, offc);
            float area = __fmul_rn(__fsub_rn(x2, x1), __fsub_rn(y2, y1));
            bx1[tid] = x1; by1[tid] = y1; bx2[tid] = x2; by2[tid] = y2;
            bar[tid] = area; bprop[tid] = prop;
        }
        unsigned long long bal = __ballot(valid);
        if (tid < KCAND && lane == 0) bvalid[wv] = bal;
    }
    __syncthreads();   // keys fully consumed -> clist may overwrite

    // ---- P6: class bucketing (clist overlays keys) ----
    if (tid < NCLS) ccnt[tid] = 0;
    if (tid < NTH * 16) keep10[tid] = 0ULL;
    __syncthreads();
    if (mycls >= 0) {
        int slot = atomicAdd(&ccnt[mycls], 1);
        if (slot < CCAP) clist[mycls * CCAP + slot] = tid;   // rank
    }
    __syncthreads();

    // ---- P7: per-class greedy NMS (16 waves x 5 classes), exact greedy ----
    for (int cl = wv; cl < NCLS; cl += 16) {
        int n = ccnt[cl];
        if (n > CCAP) n = CCAP;
        if (n == 0) continue;
        int r = (lane < n) ? clist[cl * CCAP + lane] : 0x7fffffff;
        int pos = 0;
        for (int j = 0; j < n; ++j) {
            int rj = __shfl(r, j, 64);
            pos += (rj < r) ? 1 : 0;
        }
        int srt = 0;
        for (int j = 0; j < n; ++j) {
            int pj = __shfl(pos, j, 64);
            int rj = __shfl(r, j, 64);
            if (pj == lane) srt = rj;
        }
        bool act = lane < n;
        float x1 = 0, y1 = 0, x2 = 0, y2 = 0, ar = 0;
        bool val = false;
        if (act) {
            x1 = bx1[srt]; y1 = by1[srt]; x2 = bx2[srt]; y2 = by2[srt]; ar = bar[srt];
            val = (bvalid[srt >> 6] >> (srt & 63)) & 1ULL;
        }
        unsigned long long m[NTH];
        #pragma unroll
        for (int t = 0; t < NTH; ++t) m[t] = 0ULL;
        for (int b = 0; b < n; ++b) {
            float xj1 = __shfl(x1, b, 64), yj1 = __shfl(y1, b, 64);
            float xj2 = __shfl(x2, b, 64), yj2 = __shfl(y2, b, 64);
            float aj  = __shfl(ar, b, 64);
            float iw = fmaxf(__fsub_rn(fminf(x2, xj2), fmaxf(x1, xj1)), 0.f);
            float ih = fmaxf(__fsub_rn(fminf(y2, yj2), fmaxf(y1, yj1)), 0.f);
            float inter = __fmul_rn(iw, ih);
            float uni   = __fsub_rn(__fadd_rn(ar, aj), inter);
            float iou   = (uni > 0.f) ? __fdiv_rn(inter, uni) : 0.f;
            if (act && b < lane) {
                #pragma unroll
                for (int t = 0; t < NTH; ++t)
                    if (iou > nms_th(t)) m[t] |= 1ULL << b;
            }
        }
        unsigned long long vmask = __ballot(act && val);
        for (int t = 0; t < NTH; ++t) {
            unsigned long long keep = vmask;
            for (int it = 0; it <= n; ++it) {
                bool nk = act && val && ((m[t] & keep) == 0ULL);
                unsigned long long nb = __ballot(nk);
                if (nb == keep) break;
                keep = nb;
            }
            if (act && ((keep >> lane) & 1ULL))
                atomicOr(&keep10[t * 16 + (srt >> 6)], 1ULL << (srt & 63));
        }
    }
    __syncthreads();

    // ---- P8: counts, threshold select, top-6 walk ----
    if (tid < NTH) scnt[tid] = 0;
    __syncthreads();
    if (tid < NTH * 16) {
        int pc = __popcll(keep10[tid]);
        if (pc) atomicAdd(&scnt[tid >> 4], pc);
    }
    __syncthreads();
    if (tid == 0) {
        int tsel = NTH - 1;
        for (int t = 0; t < NTH; ++t) if (scnt[t] >= NOBJ) { tsel = t; break; }
        stsel = tsel;
        int got = 0;
        const unsigned long long* kw = &keep10[tsel * 16];
        for (int k = 0; k < 16 && got < NOBJ; ++k) {
            unsigned long long x = kw[k];
            while (x && got < NOBJ) {
                int b = __builtin_ctzll(x);
                sids[got++] = bprop[k * 64 + b];
                x &= x - 1;
            }
        }
        for (int k = 0; k < 16 && got < NOBJ; ++k) {
            unsigned long long x = ~kw[k];
            while (x && got < NOBJ) {
                int b = __builtin_ctzll(x);
                sids[got++] = bprop[k * 64 + b];
                x &= x - 1;
            }
        }
    }
    __syncthreads();

    // ---- P9: transposed feature gather: out[img, d, s] = feats[img, sids[s], d] ----
    const float* fb = feats + (size_t)img * NPROP * DFEAT;
    #pragma unroll
    for (int rep = 0; rep < 2; ++rep) {
        int d = rep * 1024 + tid;
        float* ob = outp + ((size_t)img * DFEAT + d) * NOBJ;
        #pragma unroll
        for (int s = 0; s < NOBJ; ++s)
            ob[s] = fb[(size_t)sids[s] * DFEAT + d];
    }
}

extern "C" void kernel_launch(void* const* d_in, const int* in_sizes, int n_in,
                              void* d_out, int out_size, void* d_ws, size_t ws_size,
                              hipStream_t stream) {
    const float* logits = (const float*)d_in[0];
    const float* boxes  = (const float*)d_in[1];
    const float* feats  = (const float*)d_in[2];
    const int*   hw     = (const int*)d_in[3];
    float* outp = (float*)d_out;

    char* ws = (char*)d_ws;
    float*    scores = (float*)(ws + OFF_SCORES);
    unsigned* hist1  = (unsigned*)(ws + OFF_H1);

    k_softhist<<<NB * HBLK, 1024, 0, stream>>>(logits, scores, hist1);
    k_mega2<<<NB, 1024, 0, stream>>>(scores, hist1, boxes, hw, feats, outp);
}

// Round 10
// 205.259 us; speedup vs baseline: 1.1362x; 1.1362x over previous
//
#include <hip/hip_runtime.h>
#include <cmath>
#include <cstdint>

#define NB 8
#define NPROP 1000
#define NCLS 80
#define NLOG 81
#define KCAND 1024
#define NTH 10
#define DFEAT 2048
#define NOBJ 6
#define NBLK 20               // bucket blocks per image
#define BPROP 50              // proposals per bucket block
#define BKEYS (BPROP*NCLS)    // 4000 keys per block
#define CCAP 64               // per-class candidate capacity (mean ~13)

// ---------------- workspace layout (bytes) ----------------
constexpr size_t OFF_GBUCK = 0;                                        // 160*4000*8 = 5,120,000
constexpr size_t OFF_GEOFF = OFF_GBUCK + (size_t)NB * NBLK * BKEYS * 8; // 160*2048*4 = 1,310,720
constexpr size_t OFF_GHIST = OFF_GEOFF + (size_t)NB * NBLK * 2048 * 4;  // 160*2048*4 = 1,310,720

__device__ __forceinline__ float nms_th(int t) {
    // replicates float32(np.arange(0.001, 1.0, 0.1)[t])
    return (float)(0.001 + 0.1 * (double)t);
}

// monotone key: ascending u64 order == (score desc, flat idx asc) == lax.top_k order
__device__ __forceinline__ unsigned score_vkey(float v) {
    float vv = (v > 1e-4f) ? v : -1.0f;
    unsigned bits = __float_as_uint(vv);
    unsigned u = (bits & 0x80000000u) ? ~bits : (bits | 0x80000000u);
    return ~u;
}

// 1024-thread block scan over 2048 LDS bins: crossing bin for rank K.
__device__ __forceinline__ void pivot_lds(const unsigned* __restrict__ h, unsigned K,
                                          int* __restrict__ out_b, int* __restrict__ out_rem,
                                          unsigned* __restrict__ wsum) {
    int tid = threadIdx.x;
    unsigned a = h[2 * tid], b = h[2 * tid + 1];
    unsigned p = a + b;
    unsigned x = p;
    #pragma unroll
    for (int d = 1; d < 64; d <<= 1) {
        unsigned y = __shfl_up(x, (unsigned)d, 64);
        if ((tid & 63) >= d) x += y;
    }
    if ((tid & 63) == 63) wsum[tid >> 6] = x;
    __syncthreads();
    if (tid < 16) {
        unsigned w = wsum[tid];
        #pragma unroll
        for (int d = 1; d < 16; d <<= 1) {
            unsigned y = __shfl_up(w, (unsigned)d, 64);
            if (tid >= d) w += y;
        }
        wsum[tid] = w;
    }
    __syncthreads();
    unsigned wex = (tid >= 64) ? wsum[(tid >> 6) - 1] : 0u;
    unsigned E = x + wex - p;   // exclusive prefix before bin 2*tid
    if (E < K && E + a >= K)              { *out_b = 2 * tid;     *out_rem = (int)(K - E); }
    else if (E + a < K && E + a + b >= K) { *out_b = 2 * tid + 1; *out_rem = (int)(K - (E + a)); }
}

// K1: softmax -> keys stashed in LDS -> local level-1 histogram -> prefix ->
// global keys bucket-sorted by bin (+ inclusive-end offsets + hist slice).
// No score array is ever written; downstream reads only small bucket prefixes.
__global__ __launch_bounds__(1024) void k_bucket(const float* __restrict__ logits,
                                                 unsigned long long* __restrict__ gbuck,
                                                 unsigned* __restrict__ geoff,
                                                 unsigned* __restrict__ ghist) {
    __shared__ unsigned long long lkeys[BKEYS];
    __shared__ unsigned hist[2048];
    __shared__ unsigned wsum[16];
    int img = blockIdx.x / NBLK, blk = blockIdx.x % NBLK;
    int tid = threadIdx.x, wv = tid >> 6, lane = tid & 63;
    hist[tid] = 0; hist[tid + 1024] = 0;
    __syncthreads();
    for (int pl = wv; pl < BPROP; pl += 16) {
        int prop = blk * BPROP + pl;
        const float* L = logits + ((size_t)img * NPROP + prop) * NLOG;
        float l0 = L[lane];
        float l1 = (lane < 17) ? L[64 + lane] : -INFINITY;
        float m = fmaxf(l0, l1);
        #pragma unroll
        for (int o = 32; o > 0; o >>= 1) m = fmaxf(m, __shfl_xor(m, o, 64));
        float e0 = expf(l0 - m);
        float e1 = (lane < 17) ? expf(l1 - m) : 0.f;
        float s = e0 + e1;
        #pragma unroll
        for (int o = 32; o > 0; o >>= 1) s += __shfl_xor(s, o, 64);
        float p0 = e0 / s;
        unsigned vk0 = score_vkey(p0);
        lkeys[pl * NCLS + lane] =
            ((unsigned long long)vk0 << 32) | (unsigned)(prop * NCLS + lane);
        atomicAdd(&hist[vk0 >> 21], 1u);
        if (lane < 16) {
            float p1 = e1 / s;
            unsigned vk1 = score_vkey(p1);
            lkeys[pl * NCLS + 64 + lane] =
                ((unsigned long long)vk1 << 32) | (unsigned)(prop * NCLS + 64 + lane);
            atomicAdd(&hist[vk1 >> 21], 1u);
        }
    }
    __syncthreads();
    // export this block's hist slice (summed by k_finish; no zeroing needed)
    unsigned base2 = (unsigned)blockIdx.x * 2048;
    ghist[base2 + tid] = hist[tid];
    ghist[base2 + tid + 1024] = hist[tid + 1024];
    // full exclusive prefix over 2048 bins (pair per thread)
    unsigned a = hist[2 * tid], b = hist[2 * tid + 1];
    unsigned p = a + b;
    unsigned x = p;
    #pragma unroll
    for (int d = 1; d < 64; d <<= 1) {
        unsigned y = __shfl_up(x, (unsigned)d, 64);
        if ((tid & 63) >= d) x += y;
    }
    if ((tid & 63) == 63) wsum[tid >> 6] = x;
    __syncthreads();
    if (tid < 16) {
        unsigned w = wsum[tid];
        #pragma unroll
        for (int d = 1; d < 16; d <<= 1) {
            unsigned y = __shfl_up(w, (unsigned)d, 64);
            if (tid >= d) w += y;
        }
        wsum[tid] = w;
    }
    __syncthreads();
    unsigned wex = (tid >= 64) ? wsum[(tid >> 6) - 1] : 0u;
    unsigned E = x + wex - p;            // exclusive start of bin 2*tid
    geoff[base2 + 2 * tid]     = E + a;        // inclusive end bin 2*tid
    geoff[base2 + 2 * tid + 1] = E + a + b;    // inclusive end bin 2*tid+1
    __syncthreads();
    hist[2 * tid] = E;                   // convert to placement counters
    hist[2 * tid + 1] = E + a;
    __syncthreads();
    unsigned long long* gb = gbuck + (size_t)blockIdx.x * BKEYS;
    for (int i = tid; i < BKEYS; i += 1024) {
        unsigned long long key = lkeys[i];
        unsigned bin = (unsigned)(key >> 53);          // == vkey >> 21
        unsigned slot = atomicAdd(&hist[bin], 1u);
        gb[slot] = key;
    }
}

// K2: one block per image. pivot1 -> hist2 over bucket prefixes -> pivot2/T22 ->
// gather (~1030 keys) -> rank-by-count -> decode -> per-class NMS -> select ->
// feature gather. All selection math verbatim from the passing R8/R9 kernels.
// LDS overlays: A[0,20480) hist->clist ; B[20480,36864) ckeys ;
//               C[36864,61440) cand arrays ; D[61440,..) small state.
__global__ __launch_bounds__(1024) void k_finish(const unsigned long long* __restrict__ gbuck,
                                                 const unsigned* __restrict__ geoff,
                                                 const unsigned* __restrict__ ghist,
                                                 const float* __restrict__ boxes,
                                                 const int* __restrict__ hw,
                                                 const float* __restrict__ feats,
                                                 float* __restrict__ outp) {
    __shared__ __align__(16) unsigned char smem[63232];
    unsigned*           hist  = (unsigned*)(smem);                     // [2048] (phase 1-2)
    int*                clist = (int*)(smem);                          // [80*64] (phase 4+)
    unsigned long long* ckeys = (unsigned long long*)(smem + 20480);   // [2048]
    float* bx1 = (float*)(smem + 36864);
    float* by1 = (float*)(smem + 40960);
    float* bx2 = (float*)(smem + 45056);
    float* by2 = (float*)(smem + 49152);
    float* bar = (float*)(smem + 53248);
    int*   bprop = (int*)(smem + 57344);
    unsigned long long* bvalid = (unsigned long long*)(smem + 61440);  // [16]
    int*   ccnt  = (int*)(smem + 61568);                               // [80]
    unsigned long long* keep10 = (unsigned long long*)(smem + 61896);  // [10*16]
    int*   scnt  = (int*)(smem + 63176);                               // [10]
    __shared__ unsigned wsum[16];
    __shared__ int sb1, sr1, sb2, sr2;
    __shared__ int sids[NOBJ];
    __shared__ unsigned scounter;

    const int img = blockIdx.x;
    const int tid = threadIdx.x;
    const int wv  = tid >> 6, lane = tid & 63;

    // ---- P1: sum 20 hist slices; pivot1 ----
    {
        unsigned s0 = 0, s1 = 0;
        #pragma unroll
        for (int s = 0; s < NBLK; ++s) {
            const unsigned* hs = ghist + (size_t)(img * NBLK + s) * 2048;
            s0 += hs[tid];
            s1 += hs[tid + 1024];
        }
        hist[tid] = s0; hist[tid + 1024] = s1;
    }
    __syncthreads();
    pivot_lds(hist, KCAND, &sb1, &sr1, wsum);
    __syncthreads();
    int b1 = sb1, rem1 = sr1;
    __syncthreads();

    // ---- P2: level-2 histogram (vkey bits [20:10]) over bucket prefixes ----
    hist[tid] = 0; hist[tid + 1024] = 0;
    __syncthreads();
    for (int s = 0; s < NBLK; ++s) {
        int np = (int)geoff[(size_t)(img * NBLK + s) * 2048 + b1];  // elems in bins <= b1
        const unsigned long long* kb = gbuck + (size_t)(img * NBLK + s) * BKEYS;
        for (int i = tid; i < np; i += 1024) {
            unsigned vk = (unsigned)(kb[i] >> 32);
            if ((int)(vk >> 21) == b1) atomicAdd(&hist[(vk >> 10) & 2047u], 1u);
        }
    }
    __syncthreads();
    pivot_lds(hist, (unsigned)rem1, &sb2, &sr2, wsum);
    __syncthreads();
    unsigned T22 = ((unsigned)b1 << 11) | (unsigned)sb2;

    // ---- P3: gather keys with top22 <= T22 into LDS ----
    if (tid == 0) scounter = 0;
    __syncthreads();
    for (int s = 0; s < NBLK; ++s) {
        int np = (int)geoff[(size_t)(img * NBLK + s) * 2048 + b1];
        const unsigned long long* kb = gbuck + (size_t)(img * NBLK + s) * BKEYS;
        for (int i = tid; i < np; i += 1024) {
            unsigned long long key = kb[i];
            if (((unsigned)(key >> 32) >> 10) <= T22) {
                unsigned pos = atomicAdd(&scounter, 1u);
                if (pos < 2048) ckeys[pos] = key;
            }
        }
    }
    __syncthreads();
    int cnt = (int)scounter; if (cnt > 2048) cnt = 2048;

    // ---- P4: zero small state; rank-by-count; decode (exact _rn sequence) ----
    if (tid < NCLS) ccnt[tid] = 0;
    if (tid < 16) bvalid[tid] = 0ULL;
    if (tid < NTH * 16) keep10[tid] = 0ULL;
    if (tid < NTH) scnt[tid] = 0;
    __syncthreads();
    #pragma unroll
    for (int rep = 0; rep < 2; ++rep) {
        int i = rep * 1024 + tid;
        if (i < cnt) {
            unsigned long long a = ckeys[i];
            int r = 0;
            #pragma unroll 8
            for (int j = 0; j < cnt; ++j) r += (ckeys[j] < a) ? 1 : 0;
            if (r < KCAND) {
                unsigned u   = ~(unsigned)(a >> 32);
                unsigned idx = (unsigned)a;
                const unsigned uth = __float_as_uint(1e-4f) | 0x80000000u;
                bool valid = u > uth;
                int prop = (int)(idx / NCLS);
                int cls  = (int)(idx - (unsigned)prop * NCLS);
                const float4 bx = *(const float4*)(boxes + ((((size_t)img * NPROP + prop) * NCLS + cls) << 2));
                float h = (float)hw[img * 2 + 0];
                float w = (float)hw[img * 2 + 1];
                float x1 = fminf(fmaxf(bx.x, 0.f), w);
                float y1 = fminf(fmaxf(bx.y, 0.f), h);
                float x2 = fminf(fmaxf(bx.z, 0.f), w);
                float y2 = fminf(fmaxf(bx.w, 0.f), h);
                float offc = __fmul_rn((float)cls, 4096.0f);
                x1 = __fadd_rn(x1, offc); y1 = __fadd_rn(y1, offc);
                x2 = __fadd_rn(x2, offc); y2 = __fadd_rn(y2, offc);
                float area = __fmul_rn(__fsub_rn(x2, x1), __fsub_rn(y2, y1));
                bx1[r] = x1; by1[r] = y1; bx2[r] = x2; by2[r] = y2;
                bar[r] = area; bprop[r] = prop;
                if (valid) atomicOr(&bvalid[r >> 6], 1ULL << (r & 63));
                int slot = atomicAdd(&ccnt[cls], 1);
                if (slot < CCAP) clist[cls * CCAP + slot] = r;
            }
        }
    }
    __syncthreads();

    // ---- P5: per-class greedy NMS (16 waves x 5 classes), exact greedy ----
    for (int cl = wv; cl < NCLS; cl += 16) {
        int n = ccnt[cl];
        if (n > CCAP) n = CCAP;
        if (n == 0) continue;
        int r = (lane < n) ? clist[cl * CCAP + lane] : 0x7fffffff;
        int pos = 0;
        for (int j = 0; j < n; ++j) {
            int rj = __shfl(r, j, 64);
            pos += (rj < r) ? 1 : 0;
        }
        int srt = 0;
        for (int j = 0; j < n; ++j) {
            int pj = __shfl(pos, j, 64);
            int rj = __shfl(r, j, 64);
            if (pj == lane) srt = rj;
        }
        bool act = lane < n;
        float x1 = 0, y1 = 0, x2 = 0, y2 = 0, ar = 0;
        bool val = false;
        if (act) {
            x1 = bx1[srt]; y1 = by1[srt]; x2 = bx2[srt]; y2 = by2[srt]; ar = bar[srt];
            val = (bvalid[srt >> 6] >> (srt & 63)) & 1ULL;
        }
        unsigned long long m[NTH];
        #pragma unroll
        for (int t = 0; t < NTH; ++t) m[t] = 0ULL;
        for (int b = 0; b < n; ++b) {
            float xj1 = __shfl(x1, b, 64), yj1 = __shfl(y1, b, 64);
            float xj2 = __shfl(x2, b, 64), yj2 = __shfl(y2, b, 64);
            float aj  = __shfl(ar, b, 64);
            float iw = fmaxf(__fsub_rn(fminf(x2, xj2), fmaxf(x1, xj1)), 0.f);
            float ih = fmaxf(__fsub_rn(fminf(y2, yj2), fmaxf(y1, yj1)), 0.f);
            float inter = __fmul_rn(iw, ih);
            float uni   = __fsub_rn(__fadd_rn(ar, aj), inter);
            float iou   = (uni > 0.f) ? __fdiv_rn(inter, uni) : 0.f;
            if (act && b < lane) {
                #pragma unroll
                for (int t = 0; t < NTH; ++t)
                    if (iou > nms_th(t)) m[t] |= 1ULL << b;
            }
        }
        unsigned long long vmask = __ballot(act && val);
        for (int t = 0; t < NTH; ++t) {
            unsigned long long keep = vmask;
            for (int it = 0; it <= n; ++it) {
                bool nk = act && val && ((m[t] & keep) == 0ULL);
                unsigned long long nb = __ballot(nk);
                if (nb == keep) break;
                keep = nb;
            }
            if (act && ((keep >> lane) & 1ULL))
                atomicOr(&keep10[t * 16 + (srt >> 6)], 1ULL << (srt & 63));
        }
    }
    __syncthreads();

    // ---- P6: counts, threshold select, top-6 walk ----
    if (tid < NTH * 16) {
        int pc = __popcll(keep10[tid]);
        if (pc) atomicAdd(&scnt[tid >> 4], pc);
    }
    __syncthreads();
    if (tid == 0) {
        int tsel = NTH - 1;
        for (int t = 0; t < NTH; ++t) if (scnt[t] >= NOBJ) { tsel = t; break; }
        int got = 0;
        const unsigned long long* kw = &keep10[tsel * 16];
        for (int k = 0; k < 16 && got < NOBJ; ++k) {
            unsigned long long x = kw[k];
            while (x && got < NOBJ) {
                int b = __builtin_ctzll(x);
                sids[got++] = bprop[k * 64 + b];
                x &= x - 1;
            }
        }
        for (int k = 0; k < 16 && got < NOBJ; ++k) {
            unsigned long long x = ~kw[k];
            while (x && got < NOBJ) {
                int b = __builtin_ctzll(x);
                sids[got++] = bprop[k * 64 + b];
                x &= x - 1;
            }
        }
    }
    __syncthreads();

    // ---- P7: transposed feature gather: out[img, d, s] = feats[img, sids[s], d] ----
    const float* fb = feats + (size_t)img * NPROP * DFEAT;
    #pragma unroll
    for (int rep = 0; rep < 2; ++rep) {
        int d = rep * 1024 + tid;
        float* ob = outp + ((size_t)img * DFEAT + d) * NOBJ;
        #pragma unroll
        for (int s = 0; s < NOBJ; ++s)
            ob[s] = fb[(size_t)sids[s] * DFEAT + d];
    }
}

extern "C" void kernel_launch(void* const* d_in, const int* in_sizes, int n_in,
                              void* d_out, int out_size, void* d_ws, size_t ws_size,
                              hipStream_t stream) {
    const float* logits = (const float*)d_in[0];
    const float* boxes  = (const float*)d_in[1];
    const float* feats  = (const float*)d_in[2];
    const int*   hw     = (const int*)d_in[3];
    float* outp = (float*)d_out;

    char* ws = (char*)d_ws;
    unsigned long long* gbuck = (unsigned long long*)(ws + OFF_GBUCK);
    unsigned*           geoff = (unsigned*)(ws + OFF_GEOFF);
    unsigned*           ghist = (unsigned*)(ws + OFF_GHIST);

    k_bucket<<<NB * NBLK, 1024, 0, stream>>>(logits, gbuck, geoff, ghist);
    k_finish<<<NB, 1024, 0, stream>>>(gbuck, geoff, ghist, boxes, hw, feats, outp);
}